// Round 11
// baseline (525.106 us; speedup 1.0000x reference)
//
#include <hip/hip_runtime.h>
#include <cstdint>
#include <cstddef>

// GAT layer, N=8192, F_in=512, F_out=64, fp32, int32 adjacency.
//   k_pack   : adj (268 MB int32) -> bitmask (8 MB), ballot-based, BW-bound.
//   k_wh     : Wh = h@W ; wh1/wh2 projections ; global max(wh2) via atomicMax ;
//              PBhi/PBlo = 2-way bf16 split of Wh^T pre-packed in MFMA
//              B-fragment order: [tile64j][kstep][nb][lane(jg*16+fl)] 16B granules
//   k_attend : NO LDS, NO barriers. Per 16-row wave, stream 64-j tiles;
//              p = bit ? exp(lrelu(.)-Mi) : 0 in MFMA A-frag registers;
//              B-frags loaded coalesced (base+lane*16) from L2-resident PB;
//              PV = 3 mfma_f32_16x16x32_bf16 per (kstep,nb): PhBh+PlBh+PhBl.
//   k_merge  : out = sum(o)/sum(l) over JSPLIT partials
//
// R9 lesson: readfirstlane-uniform LDS dest changed nothing (waterfall theory
// falsified). k_attend's ~10x gap vs pipe arithmetic is pinned on the
// barrier-per-tile + gload_lds + lgkmcnt structure itself -> removed wholesale.

#define GAT_N    8192
#define GAT_FIN  512
#define GAT_F    64
#define TJ       64
#define JSPLIT   16
#define JCHUNK   (GAT_N / JSPLIT)     // 512
#define NTILES   (JCHUNK / TJ)        // 8
#define NWORDS   (GAT_N / 64)         // 128 words per row

typedef __attribute__((ext_vector_type(8))) short short8;
typedef __attribute__((ext_vector_type(4))) float f32x4;

__device__ __forceinline__ float lrelu(float x) { return fmaxf(x, 0.2f * x); }

__device__ __forceinline__ unsigned enc_f32(float f) {
    unsigned b = __float_as_uint(f);
    return b ^ ((b & 0x80000000u) ? 0xFFFFFFFFu : 0x80000000u);
}
__device__ __forceinline__ float dec_f32(unsigned u) {
    return __uint_as_float(u ^ ((u & 0x80000000u) ? 0x80000000u : 0xFFFFFFFFu));
}
// truncation bf16 split (residual captured exactly by subtract)
__device__ __forceinline__ short f2bf_trunc(float f) {
    return (short)(__float_as_uint(f) >> 16);
}
__device__ __forceinline__ float bfhi(float f) {
    return __uint_as_float(__float_as_uint(f) & 0xFFFF0000u);
}

__device__ __forceinline__ void gload_lds16(const void* g, void* l) {
    __builtin_amdgcn_global_load_lds(
        (const __attribute__((address_space(1))) void*)g,
        (__attribute__((address_space(3))) void*)l, 16, 0, 0);
}

__device__ __forceinline__ short8 as_short8(const int4& v) {
    union { int4 i; short8 s; } u; u.i = v; return u.s;
}

// ---------------------------------------------------------------- kernel 0
// grid 1024, block 256 (4 waves). Wave handles 256 consecutive uint64 words;
// per iter 8 words: lane reads adj[word*64+lane] (256B/instr coalesced),
// ballot -> word, lane 0 stores 4x16B.
__global__ __launch_bounds__(256) void k_pack(
    const int* __restrict__ adj, unsigned long long* __restrict__ packed)
{
    const int lane = threadIdx.x & 63;
    const int wv   = blockIdx.x * 4 + (threadIdx.x >> 6);  // 4096 waves
    const size_t wbase = (size_t)wv * 256;
    for (int it = 0; it < 32; ++it) {
        const size_t w0 = wbase + (size_t)it * 8;
        const int* src = adj + w0 * 64 + lane;
        unsigned long long b0, b1, b2, b3, b4, b5, b6, b7;
        b0 = __ballot(src[0 * 64] > 0);
        b1 = __ballot(src[1 * 64] > 0);
        b2 = __ballot(src[2 * 64] > 0);
        b3 = __ballot(src[3 * 64] > 0);
        b4 = __ballot(src[4 * 64] > 0);
        b5 = __ballot(src[5 * 64] > 0);
        b6 = __ballot(src[6 * 64] > 0);
        b7 = __ballot(src[7 * 64] > 0);
        if (lane == 0) {
            ulonglong2* dst = (ulonglong2*)&packed[w0];
            dst[0] = {b0, b1};
            dst[1] = {b2, b3};
            dst[2] = {b4, b5};
            dst[3] = {b6, b7};
        }
    }
}

// ---------------------------------------------------------------- kernel 1
// grid 512, block 256: 16 rows/block (rows of Wh = j-dim), thread=(rp,f4).
// W staged in LDS 64-k chunks (2x16 KB dbuf, uniform-dest gload_lds).
// Emits wh1/wh2/max and PBhi/PBlo: B-fragment-packed bf16 split of Wh^T.
// Block covers quarter-tile q=bx&3 of j-tile tt=bx>>2: kstep s=q>>1,
// jg in {(q&1)*2, (q&1)*2+1}.
__global__ __launch_bounds__(256) void k_wh(
    const float* __restrict__ h, const float* __restrict__ W,
    const float* __restrict__ a,
    float* __restrict__ wh1, float* __restrict__ wh2,
    unsigned int* __restrict__ mw2,
    char* __restrict__ pbHi, char* __restrict__ pbLo)
{
    __shared__ float sW[2][64 * GAT_F];       // 2 x 16 KB
    __shared__ unsigned short sTh[GAT_F][16]; // 2 KB
    __shared__ unsigned short sTl[GAT_F][16]; // 2 KB
    __shared__ unsigned int smax[16];
    const int tid  = threadIdx.x;
    const int lane = tid & 63;
    const int wq   = __builtin_amdgcn_readfirstlane(tid >> 6);
    const size_t r0 = (size_t)blockIdx.x * 16;
    const int rp = tid >> 4;
    const int f4 = (tid & 15) * 4;

    int Bg[4];
#pragma unroll
    for (int c = 0; c < 4; ++c) Bg[c] = wq * 64 + c * 256;

    const char* wsrc = (const char*)W;
    {   // stage chunk 0
        char* dst = (char*)sW[0];
#pragma unroll
        for (int c = 0; c < 4; ++c)
            gload_lds16(wsrc + (size_t)(Bg[c] + lane) * 16, dst + Bg[c] * 16);
    }

    const float* ha = h + (r0 + rp) * GAT_FIN;
    float4 acc = {0.f, 0.f, 0.f, 0.f};

    for (int ck = 0; ck < 8; ++ck) {
        __syncthreads();
        if (ck + 1 < 8) {
            const char* src = wsrc + (size_t)(ck + 1) * 16384;
            char* dst = (char*)sW[(ck + 1) & 1];
#pragma unroll
            for (int c = 0; c < 4; ++c)
                gload_lds16(src + (size_t)(Bg[c] + lane) * 16, dst + Bg[c] * 16);
        }
        const float* wcp = sW[ck & 1];
#pragma unroll 4
        for (int k4 = 0; k4 < 16; ++k4) {
            float4 hv = *(const float4*)&ha[ck * 64 + k4 * 4];
            const float* hvf = (const float*)&hv;
#pragma unroll
            for (int kk = 0; kk < 4; ++kk) {
                float4 wv = *(const float4*)&wcp[(k4 * 4 + kk) * GAT_F + f4];
                acc.x = fmaf(hvf[kk], wv.x, acc.x);
                acc.y = fmaf(hvf[kk], wv.y, acc.y);
                acc.z = fmaf(hvf[kk], wv.z, acc.z);
                acc.w = fmaf(hvf[kk], wv.w, acc.w);
            }
        }
    }

    // wh1/wh2 projections (reduce over f within 16-lane groups)
    float4 a1 = *(const float4*)&a[f4];
    float4 a2 = *(const float4*)&a[GAT_F + f4];
    float pa = acc.x*a1.x + acc.y*a1.y + acc.z*a1.z + acc.w*a1.w;
    float pb = acc.x*a2.x + acc.y*a2.y + acc.z*a2.z + acc.w*a2.w;
#pragma unroll
    for (int m = 1; m < 16; m <<= 1) {
        pa += __shfl_xor(pa, m);
        pb += __shfl_xor(pb, m);
    }
    if ((tid & 15) == 0) {
        wh1[r0 + rp] = pa;
        wh2[r0 + rp] = pb;
        smax[rp] = enc_f32(pb);
    }

    // bf16 split -> LDS transpose buffers  (sT[f][rp])
    const float* af = (const float*)&acc;
#pragma unroll
    for (int e = 0; e < 4; ++e) {
        float v = af[e];
        sTh[f4 + e][rp] = (unsigned short)f2bf_trunc(v);
        sTl[f4 + e][rp] = (unsigned short)f2bf_trunc(v - bfhi(v));
    }
    __syncthreads();

    {   // write B-frag granules: thread = (hf, nb, jgo, fl) -> 16B
        const int tt  = blockIdx.x >> 2;
        const int q   = blockIdx.x & 3;
        const int s   = q >> 1;
        const int hf  = tid >> 7;
        const int rem = tid & 127;
        const int nb  = rem >> 5;
        const int jgo = (rem >> 4) & 1;
        const int fl  = rem & 15;
        const int jga = (q & 1) * 2 + jgo;            // global jg 0..3
        const unsigned short* st = hf ? &sTl[nb * 16 + fl][jgo * 8]
                                      : &sTh[nb * 16 + fl][jgo * 8];
        uint4 v = *(const uint4*)st;                  // 8 bf16 = 16B
        char* base = hf ? pbLo : pbHi;
        *(uint4*)(base + (size_t)tt * 8192 + s * 4096 + nb * 1024
                       + (jga * 16 + fl) * 16) = v;
    }
    if (tid == 0) {
        unsigned m = smax[0];
#pragma unroll
        for (int r = 1; r < 16; ++r) m = max(m, smax[r]);
        atomicMax(mw2, m);
    }
}

// ---------------------------------------------------------------- kernel 2
// grid (128, 16), block 256 (4 waves x 16 rows; waves fully independent).
// ZERO barriers, zero LDS. Per 64-j tile: A-frag p from bitmask+wh2+exp;
// B-frags loaded coalesced from PB (uniform base + lane*16) into VGPRs,
// software-pipelined one kstep ahead; 24 MFMA/tile.
__global__ __launch_bounds__(256, 3) void k_attend(
    const unsigned long long* __restrict__ packed,
    const char* __restrict__ pbHi, const char* __restrict__ pbLo,
    const float* __restrict__ wh1, const float* __restrict__ wh2,
    const unsigned int* __restrict__ mw2,
    float* __restrict__ po, float* __restrict__ pl)
{
    const int tid  = threadIdx.x;
    const int w    = tid >> 6;
    const int lane = tid & 63;
    const int fl   = lane & 15;
    const int jg   = lane >> 4;
    const int rw   = blockIdx.x * 64 + w * 16;
    const int j0   = blockIdx.y * JCHUNK;

    const float Mw2 = dec_f32(*mw2);
    const float ai  = wh1[rw + fl];           // this lane's row
    const float Mi  = lrelu(ai + Mw2);        // safe rowmax bound

    // B-frag pointers: + t*8192 + s*4096 + nb*1024
    const char* bh0 = pbHi + (size_t)(j0 >> 6) * 8192 + lane * 16;
    const char* bl0 = pbLo + (size_t)(j0 >> 6) * 8192 + lane * 16;

    const unsigned long long* mp = packed + (size_t)(rw + fl) * NWORDS + (j0 >> 6);
    const float* wp = wh2 + j0 + jg * 8;

    // ---- prologue: tile-0 kstep-0 B frags + tile-0 mask
    int4 B0h[4], B0l[4], B1h[4], B1l[4];
#pragma unroll
    for (int nb = 0; nb < 4; ++nb) {
        B0h[nb] = *(const int4*)(bh0 + nb * 1024);
        B0l[nb] = *(const int4*)(bl0 + nb * 1024);
    }
    unsigned long long amc = mp[0];

    f32x4 acc[4] = {};                        // C tiles for 4 f-blocks
    float psum = 0.f;

    for (int t = 0; t < NTILES; ++t) {
        // prefetch next tile's mask
        const int tn = (t + 1 < NTILES) ? t + 1 : t;
        unsigned long long amn = mp[tn];

        // issue kstep-1 B loads (used after kstep-0 compute)
        {
            const char* bh = bh0 + t * 8192 + 4096;
            const char* bl = bl0 + t * 8192 + 4096;
#pragma unroll
            for (int nb = 0; nb < 4; ++nb) {
                B1h[nb] = *(const int4*)(bh + nb * 1024);
                B1l[nb] = *(const int4*)(bl + nb * 1024);
            }
        }

        // ---- kstep 0: j = t*64 + jg*8 + e
        {
            const float4 wA = *(const float4*)(wp + t * TJ);
            const float4 wB = *(const float4*)(wp + t * TJ + 4);
            const unsigned m8 = (unsigned)(amc >> (jg * 8)) & 0xFFu;
            float pv[8];
            const float* wAf = (const float*)&wA;
            const float* wBf = (const float*)&wB;
#pragma unroll
            for (int e = 0; e < 4; ++e) {
                pv[e]     = ((m8 >> e) & 1u)       ? __expf(lrelu(ai + wAf[e]) - Mi) : 0.f;
                pv[4 + e] = ((m8 >> (4 + e)) & 1u) ? __expf(lrelu(ai + wBf[e]) - Mi) : 0.f;
            }
            short8 ph, plo;
#pragma unroll
            for (int e = 0; e < 8; ++e) {
                psum  += pv[e];
                ph[e]  = f2bf_trunc(pv[e]);
                plo[e] = f2bf_trunc(pv[e] - bfhi(pv[e]));
            }
#pragma unroll
            for (int nb = 0; nb < 4; ++nb) {
                short8 bh = as_short8(B0h[nb]);
                short8 bl = as_short8(B0l[nb]);
                acc[nb] = __builtin_amdgcn_mfma_f32_16x16x32_bf16(ph,  bh, acc[nb], 0, 0, 0);
                acc[nb] = __builtin_amdgcn_mfma_f32_16x16x32_bf16(plo, bh, acc[nb], 0, 0, 0);
                acc[nb] = __builtin_amdgcn_mfma_f32_16x16x32_bf16(ph,  bl, acc[nb], 0, 0, 0);
            }
        }

        // issue next-tile kstep-0 B loads (used after kstep-1 compute)
        {
            const char* bh = bh0 + tn * 8192;
            const char* bl = bl0 + tn * 8192;
#pragma unroll
            for (int nb = 0; nb < 4; ++nb) {
                B0h[nb] = *(const int4*)(bh + nb * 1024);
                B0l[nb] = *(const int4*)(bl + nb * 1024);
            }
        }

        // ---- kstep 1: j = t*64 + 32 + jg*8 + e
        {
            const float4 wA = *(const float4*)(wp + t * TJ + 32);
            const float4 wB = *(const float4*)(wp + t * TJ + 36);
            const unsigned m8 = (unsigned)(amc >> (32 + jg * 8)) & 0xFFu;
            float pv[8];
            const float* wAf = (const float*)&wA;
            const float* wBf = (const float*)&wB;
#pragma unroll
            for (int e = 0; e < 4; ++e) {
                pv[e]     = ((m8 >> e) & 1u)       ? __expf(lrelu(ai + wAf[e]) - Mi) : 0.f;
                pv[4 + e] = ((m8 >> (4 + e)) & 1u) ? __expf(lrelu(ai + wBf[e]) - Mi) : 0.f;
            }
            short8 ph, plo;
#pragma unroll
            for (int e = 0; e < 8; ++e) {
                psum  += pv[e];
                ph[e]  = f2bf_trunc(pv[e]);
                plo[e] = f2bf_trunc(pv[e] - bfhi(pv[e]));
            }
#pragma unroll
            for (int nb = 0; nb < 4; ++nb) {
                short8 bh = as_short8(B1h[nb]);
                short8 bl = as_short8(B1l[nb]);
                acc[nb] = __builtin_amdgcn_mfma_f32_16x16x32_bf16(ph,  bh, acc[nb], 0, 0, 0);
                acc[nb] = __builtin_amdgcn_mfma_f32_16x16x32_bf16(plo, bh, acc[nb], 0, 0, 0);
                acc[nb] = __builtin_amdgcn_mfma_f32_16x16x32_bf16(ph,  bl, acc[nb], 0, 0, 0);
            }
        }

        amc = amn;
    }

    // ---- epilogue: row sums (4 jg-groups hold partial sums per row)
    psum += __shfl_xor(psum, 16);
    psum += __shfl_xor(psum, 32);
    if (lane < 16)
        pl[(size_t)blockIdx.y * GAT_N + rw + lane] = psum;

    // C layout (m89): col = lane&15 (=f within block), row = (lane>>4)*4 + reg
    const size_t ob = ((size_t)blockIdx.y * GAT_N + rw + jg * 4) * GAT_F + fl;
#pragma unroll
    for (int nb = 0; nb < 4; ++nb) {
#pragma unroll
        for (int r = 0; r < 4; ++r)
            po[ob + (size_t)r * GAT_F + nb * 16] = acc[nb][r];
    }
}

// ---------------------------------------------------------------- kernel 3
__global__ __launch_bounds__(256) void k_merge(
    const float* __restrict__ po, const float* __restrict__ pl,
    float* __restrict__ out)
{
    const int idx = blockIdx.x * 256 + threadIdx.x;   // = i*64 + f
    const int i = idx >> 6;
    float s = 0.f, ls = 0.f;
#pragma unroll
    for (int y = 0; y < JSPLIT; ++y) {
        s  += po[(size_t)y * GAT_N * GAT_F + idx];
        ls += pl[(size_t)y * GAT_N + i];
    }
    out[idx] = s / ls;
}

// ---------------------------------------------------------------- launch
extern "C" void kernel_launch(void* const* d_in, const int* in_sizes, int n_in,
                              void* d_out, int out_size, void* d_ws, size_t ws_size,
                              hipStream_t stream) {
    (void)in_sizes; (void)n_in; (void)out_size; (void)ws_size;
    const float* h   = (const float*)d_in[0];
    const int*   adj = (const int*)d_in[1];
    const float* W   = (const float*)d_in[2];
    const float* a   = (const float*)d_in[3];
    float* out = (float*)d_out;

    char* wsb = (char*)d_ws;
    float*              wh1    = (float*)(wsb);                     // 32 KB
    float*              wh2    = (float*)(wsb + 32768);             // 32 KB
    unsigned int*       mw2    = (unsigned int*)(wsb + 65536);      // 4 B
    unsigned long long* packed = (unsigned long long*)(wsb + 131072); // 8 MB
    char*               pbHi   = (wsb + 8519680);                   // 1 MB
    char*               pbLo   = (wsb + 9568256);                   // 1 MB
    float*              po     = (float*)(wsb + 10616832);          // 32 MB
    float*              pl     = (float*)(wsb + 44171264);          // 512 KB

    hipMemsetAsync(mw2, 0, 4, stream);        // enc: 0 < every real value
    k_pack  <<<1024, 256, 0, stream>>>(adj, packed);
    k_wh    <<<GAT_N / 16, 256, 0, stream>>>(h, W, a, wh1, wh2, mw2, pbHi, pbLo);
    k_attend<<<dim3(GAT_N / 64, JSPLIT), 256, 0, stream>>>(packed, pbHi, pbLo,
                                                           wh1, wh2, mw2, po, pl);
    k_merge <<<GAT_N * GAT_F / 256, 256, 0, stream>>>(po, pl, out);
}